// Round 11
// baseline (1098.777 us; speedup 1.0000x reference)
//
#include <hip/hip_runtime.h>

#define HID 128
#define EPSF 1e-6f

__device__ inline unsigned f2bf(float f) {
  unsigned u = __float_as_uint(f);
  return (u + 0x7fffu + ((u >> 16) & 1u)) >> 16;  // RNE
}
__device__ inline float bf2f_lo(unsigned u) { return __uint_as_float(u << 16); }
__device__ inline float bf2f_hi(unsigned u) { return __uint_as_float(u & 0xFFFF0000u); }

// ------- fused: histogram of x (65 bins) + per-row edge count + slot capture -------
__global__ void k_histcnt(const int* __restrict__ x, int n, const int* __restrict__ row,
                          int e, int* __restrict__ hist, int* __restrict__ cnt,
                          int* __restrict__ slot) {
  __shared__ int lh[65];
  int t = threadIdx.x;
  if (t < 65) lh[t] = 0;
  __syncthreads();
  int tid = blockIdx.x * blockDim.x + t, stride = gridDim.x * blockDim.x;
  for (int i = tid; i < e; i += stride) slot[i] = atomicAdd(&cnt[row[i]], 1);
  for (int i = tid; i < n; i += stride) atomicAdd(&lh[x[i]], 1);
  __syncthreads();
  if (t < 65 && lh[t]) atomicAdd(&hist[t], lh[t]);
}

// ---------------- 3-phase exclusive scan over cnt[0..n) -> rowptr ----------------
__global__ void k_scan_partial(const int* __restrict__ cnt, int n, int* __restrict__ bsum) {
  __shared__ int sh[256];
  int t = threadIdx.x;
  int base = blockIdx.x * 2048 + t * 8;
  int s = 0;
#pragma unroll
  for (int j = 0; j < 8; ++j) { int idx = base + j; if (idx < n) s += cnt[idx]; }
  sh[t] = s; __syncthreads();
  for (int off = 128; off > 0; off >>= 1) {
    if (t < off) sh[t] += sh[t + off];
    __syncthreads();
  }
  if (t == 0) bsum[blockIdx.x] = sh[0];
}

__global__ void k_scan_bsum(int* __restrict__ bsum, int nb) {
  if (threadIdx.x == 0 && blockIdx.x == 0) {
    int acc = 0;
    for (int i = 0; i < nb; ++i) { int v = bsum[i]; bsum[i] = acc; acc += v; }
  }
}

__global__ void k_scan_final(const int* __restrict__ cnt, int n, const int* __restrict__ bsum,
                             int* __restrict__ rowptr) {
  __shared__ int sh[256];
  int t = threadIdx.x;
  int base = blockIdx.x * 2048 + t * 8;
  int v[8]; int s = 0;
#pragma unroll
  for (int j = 0; j < 8; ++j) { int idx = base + j; v[j] = (idx < n) ? cnt[idx] : 0; s += v[j]; }
  sh[t] = s; __syncthreads();
  for (int off = 1; off < 256; off <<= 1) {
    int val = (t >= off) ? sh[t - off] : 0;
    __syncthreads();
    sh[t] += val;
    __syncthreads();
  }
  int off0 = bsum[blockIdx.x] + sh[t] - s;  // exclusive prefix for this thread
#pragma unroll
  for (int j = 0; j < 8; ++j) {
    int idx = base + j;
    if (idx < n) { rowptr[idx] = off0; off0 += v[j]; }
  }
}

// ------- scatter edges into CSR order: atomic-free, pos = rowptr[r] + slot[i] -------
__global__ __launch_bounds__(256) void k_scatter(
    const int* __restrict__ row, const int* __restrict__ col,
    const float* __restrict__ ew, const int* __restrict__ x,
    const int* __restrict__ rowptr, const int* __restrict__ slot, int e,
    int2* __restrict__ sedge) {
  int tid = blockIdx.x * blockDim.x + threadIdx.x;
  int stride = gridDim.x * blockDim.x;
  for (int i0 = tid; i0 < e; i0 += stride * 4) {
    int r[4], c[4], s[4], xc[4], rp[4]; float w[4]; bool valid[4];
#pragma unroll
    for (int k = 0; k < 4; ++k) {
      int i = i0 + k * stride; valid[k] = (i < e);
      if (valid[k]) { r[k] = row[i]; c[k] = col[i]; w[k] = ew[i]; s[k] = slot[i]; }
    }
#pragma unroll
    for (int k = 0; k < 4; ++k) if (valid[k]) { xc[k] = x[c[k]]; rp[k] = rowptr[r[k]]; }
#pragma unroll
    for (int k = 0; k < 4; ++k)
      if (valid[k]) sedge[rp[k] + s[k]] = make_int2(c[k] | (xc[k] << 17), __float_as_int(w[k]));
  }
}

// ---------------- fold GN0 into bf16-packed embedding table ----------------
__global__ void k_gn0(const float* __restrict__ emb, const int* __restrict__ hist,
                      const float* __restrict__ gw, const float* __restrict__ gb,
                      const float* __restrict__ gms, float invN,
                      unsigned* __restrict__ emb1b) {
  int t = threadIdx.x;  // 64 threads; cols d0=2t, d1=2t+1
  int d0 = t * 2, d1 = t * 2 + 1;
  float s0 = 0, s20 = 0, s1 = 0, s21 = 0;
  for (int k = 0; k < 65; ++k) {
    float c = (float)hist[k];
    float v0 = emb[k * HID + d0], v1 = emb[k * HID + d1];
    s0 += c * v0; s20 += c * v0 * v0;
    s1 += c * v1; s21 += c * v1 * v1;
  }
  float m0 = s0 * invN, E20 = s20 * invN;
  float m1 = s1 * invN, E21 = s21 * invN;
  float sh0 = m0 * gms[d0], sh1 = m1 * gms[d1];
  float aa0 = gw[d0] / sqrtf(E20 - 2.f * sh0 * m0 + sh0 * sh0 + EPSF);
  float aa1 = gw[d1] / sqrtf(E21 - 2.f * sh1 * m1 + sh1 * sh1 + EPSF);
  float cc0 = gb[d0] - aa0 * sh0, cc1 = gb[d1] - aa1 * sh1;
  for (int k = 0; k < 65; ++k) {
    float y0 = fmaf(aa0, emb[k * HID + d0], cc0);
    float y1 = fmaf(aa1, emb[k * HID + d1], cc1);
    emb1b[k * (HID / 2) + t] = f2bf(y0) | (f2bf(y1) << 16);
  }
}

// ---- chained double-GraphNorm -> affine; optionally fold int8 dequant scale --------
__global__ void k_gnchain(const float* __restrict__ gsum, const float* __restrict__ gsq,
                          float invN, const float* __restrict__ gw, const float* __restrict__ gb,
                          const float* __restrict__ gms, int i1, int i2,
                          float* __restrict__ A, float* __restrict__ C,
                          const float* __restrict__ hmax, float* __restrict__ Aq,
                          float* __restrict__ qinv) {
  int d = threadIdx.x;  // 128 threads
  float m = gsum[d] * invN, E2 = gsq[d] * invN;
  float ms1 = gms[i1 * HID + d], w1 = gw[i1 * HID + d], b1 = gb[i1 * HID + d];
  float sh1 = m * ms1;
  float a1 = w1 / sqrtf(E2 - 2.f * sh1 * m + sh1 * sh1 + EPSF);
  float c1 = b1 - a1 * sh1;
  float m2 = a1 * m + c1;
  float E2b = a1 * a1 * E2 + 2.f * a1 * c1 * m + c1 * c1;
  float ms2 = gms[i2 * HID + d], w2 = gw[i2 * HID + d], b2 = gb[i2 * HID + d];
  float sh2 = m2 * ms2;
  float a2 = w2 / sqrtf(E2b - 2.f * sh2 * m2 + sh2 * sh2 + EPSF);
  float c2 = b2 - a2 * sh2;
  float Af = a2 * a1, Cf = a2 * c1 + c2;
  A[d] = Af; C[d] = Cf;
  if (hmax) {
    float h = hmax[d];                       // max |h2| per column (bf16-rounded domain)
    Aq[d] = Af * (h * (1.0f / 127.0f));      // dequant folded into affine
    qinv[d] = (h > 0.f) ? 127.0f / h : 0.f;
  }
}

// == SpMM1: work-stealing wave-per-node, bf16 LDS table, batch-32 one-epoch, hmax ====
__global__ __launch_bounds__(256) void k_spmm1(
    const int* __restrict__ rowptr, const int2* __restrict__ sedge,
    const unsigned* __restrict__ emb1b, int n, int* __restrict__ wc,
    unsigned* __restrict__ h2b, float* __restrict__ gsum, float* __restrict__ gsq,
    unsigned* __restrict__ hmax) {
  __shared__ unsigned lemb[65 * 64];
  __shared__ float red[2][4][64][2];
  __shared__ float rmx[4][64][2];
  int t = threadIdx.x;
  for (int i = t; i < 65 * 64; i += 256) lemb[i] = emb1b[i];
  __syncthreads();
  int l = t & 63, wv = t >> 6;
  float ps0 = 0, ps1 = 0, q0s = 0, q1s = 0, m0 = 0, m1 = 0;
  for (;;) {
    int start = 0;
    if (l == 0) start = atomicAdd(wc, 4);
    start = __shfl(start, 0, 64);
    if (start >= n) break;
    int nend = min(start + 4, n);
    for (int node = start; node < nend; ++node) {
      int p0 = rowptr[node], p1 = rowptr[node + 1];
      float wsum = 0.f, a0 = 0.f, a1 = 0.f;
      for (int base = p0; base < p1; base += 32) {
        int rem = p1 - base;
        float w[32]; int xc[32];
#pragma unroll
        for (int k = 0; k < 16; ++k) {
          int idx = base + k;
          int2 bb = sedge[idx < p1 ? idx : p1 - 1];
          w[k] = (idx < p1) ? __int_as_float(bb.y) : 0.f;
          xc[k] = (int)((unsigned)bb.x >> 17);
        }
        if (rem > 16) {
#pragma unroll
          for (int k = 16; k < 32; ++k) {
            int idx = base + k;
            int2 bb = sedge[idx < p1 ? idx : p1 - 1];
            w[k] = (idx < p1) ? __int_as_float(bb.y) : 0.f;
            xc[k] = (int)((unsigned)bb.x >> 17);
          }
        }
#pragma unroll
        for (int k = 0; k < 16; ++k) {
          unsigned v = lemb[(unsigned)xc[k] * 64 + l];
          wsum += w[k];
          a0 = fmaf(w[k], bf2f_lo(v), a0);
          a1 = fmaf(w[k], bf2f_hi(v), a1);
        }
        if (rem > 16) {
#pragma unroll
          for (int k = 16; k < 32; ++k) {
            unsigned v = lemb[(unsigned)xc[k] * 64 + l];
            wsum += w[k];
            a0 = fmaf(w[k], bf2f_lo(v), a0);
            a1 = fmaf(w[k], bf2f_hi(v), a1);
          }
        }
      }
      float d = (wsum < 0.5f) ? wsum + 1.0f : wsum;
      float invd = 1.0f / d;
      a0 *= invd; a1 *= invd;
      unsigned b0 = f2bf(a0), b1 = f2bf(a1);
      h2b[(size_t)node * 64 + l] = b0 | (b1 << 16);
      m0 = fmaxf(m0, fabsf(__uint_as_float(b0 << 16)));
      m1 = fmaxf(m1, fabsf(__uint_as_float(b1 << 16)));
      ps0 += a0; ps1 += a1; q0s += a0 * a0; q1s += a1 * a1;
    }
  }
  red[0][wv][l][0] = ps0; red[0][wv][l][1] = ps1;
  red[1][wv][l][0] = q0s; red[1][wv][l][1] = q1s;
  rmx[wv][l][0] = m0; rmx[wv][l][1] = m1;
  __syncthreads();
  if (wv == 0) {
    float s0 = 0, s1 = 0, t0 = 0, t1 = 0, x0 = 0, x1 = 0;
#pragma unroll
    for (int k = 0; k < 4; ++k) {
      s0 += red[0][k][l][0]; s1 += red[0][k][l][1];
      t0 += red[1][k][l][0]; t1 += red[1][k][l][1];
      x0 = fmaxf(x0, rmx[k][l][0]); x1 = fmaxf(x1, rmx[k][l][1]);
    }
    atomicAdd(&gsum[l * 2], s0); atomicAdd(&gsum[l * 2 + 1], s1);
    atomicAdd(&gsq[l * 2], t0);  atomicAdd(&gsq[l * 2 + 1], t1);
    atomicMax(&hmax[l * 2], __float_as_uint(x0));       // positive floats order as uints
    atomicMax(&hmax[l * 2 + 1], __float_as_uint(x1));
  }
}

// ---------------- quantize h2 (bf16) -> int8 per-column scale ----------------
__global__ __launch_bounds__(256) void k_quant(const unsigned* __restrict__ h2b,
                                               const float* __restrict__ qinv, int n,
                                               unsigned* __restrict__ qmat) {
  int stride = gridDim.x * blockDim.x;
  int total = n * 32;  // 4-col groups
  for (int idx = blockIdx.x * blockDim.x + threadIdx.x; idx < total; idx += stride) {
    int node = idx >> 5, g = idx & 31;
    const unsigned* src = &h2b[(size_t)node * 64 + g * 2];
    unsigned v0 = src[0], v1 = src[1];
    float4 qv = *(const float4*)&qinv[g * 4];
    int c0 = (int)rintf(bf2f_lo(v0) * qv.x);
    int c1 = (int)rintf(bf2f_hi(v0) * qv.y);
    int c2 = (int)rintf(bf2f_lo(v1) * qv.z);
    int c3 = (int)rintf(bf2f_hi(v1) * qv.w);
    qmat[idx] = (unsigned)(c0 & 0xFF) | ((unsigned)(c1 & 0xFF) << 8) |
                ((unsigned)(c2 & 0xFF) << 16) | ((unsigned)(c3 & 0xFF) << 24);
  }
}

// == SpMM2: work-stealing wave-per-node, batch-32 one-epoch, nt int8 gathers ========
__global__ __launch_bounds__(256) void k_spmm2(
    const int* __restrict__ rowptr, const int2* __restrict__ sedge,
    const unsigned char* __restrict__ qmat,
    const float* __restrict__ Aq, const float* __restrict__ C,
    int n, int* __restrict__ wc, float* __restrict__ out,
    float* __restrict__ gsum, float* __restrict__ gsq) {
  __shared__ float red[2][4][64][2];
  int t = threadIdx.x;
  int l = t & 63, wv = t >> 6;
  float A0 = Aq[l * 2], A1 = Aq[l * 2 + 1], C0 = C[l * 2], C1 = C[l * 2 + 1];
  float ps0 = 0, ps1 = 0, q0s = 0, q1s = 0;
  for (;;) {
    int start = 0;
    if (l == 0) start = atomicAdd(wc, 4);
    start = __shfl(start, 0, 64);
    if (start >= n) break;
    int nend = min(start + 4, n);
    for (int node = start; node < nend; ++node) {
      int p0 = rowptr[node], p1 = rowptr[node + 1];
      float wsum = 0.f, a0 = 0.f, a1 = 0.f;
      for (int base = p0; base < p1; base += 32) {
        int rem = p1 - base;
        float w[32]; unsigned short u[32];
#pragma unroll
        for (int k = 0; k < 16; ++k) {
          int idx = base + k;
          int2 bb = sedge[idx < p1 ? idx : p1 - 1];
          w[k] = (idx < p1) ? __int_as_float(bb.y) : 0.f;
          u[k] = __builtin_nontemporal_load(
              (const unsigned short*)&qmat[(size_t)(bb.x & 0x1FFFF) * 128 + l * 2]);
        }
        if (rem > 16) {
#pragma unroll
          for (int k = 16; k < 32; ++k) {
            int idx = base + k;
            int2 bb = sedge[idx < p1 ? idx : p1 - 1];
            w[k] = (idx < p1) ? __int_as_float(bb.y) : 0.f;
            u[k] = __builtin_nontemporal_load(
                (const unsigned short*)&qmat[(size_t)(bb.x & 0x1FFFF) * 128 + l * 2]);
          }
        }
#pragma unroll
        for (int k = 0; k < 16; ++k) {
          wsum += w[k];
          float y0 = fmaxf(fmaf(A0, (float)(signed char)(u[k] & 0xFF), C0), 0.f);
          float y1 = fmaxf(fmaf(A1, (float)(signed char)(u[k] >> 8), C1), 0.f);
          a0 = fmaf(w[k], y0, a0);
          a1 = fmaf(w[k], y1, a1);
        }
        if (rem > 16) {
#pragma unroll
          for (int k = 16; k < 32; ++k) {
            wsum += w[k];
            float y0 = fmaxf(fmaf(A0, (float)(signed char)(u[k] & 0xFF), C0), 0.f);
            float y1 = fmaxf(fmaf(A1, (float)(signed char)(u[k] >> 8), C1), 0.f);
            a0 = fmaf(w[k], y0, a0);
            a1 = fmaf(w[k], y1, a1);
          }
        }
      }
      float d = (wsum < 0.5f) ? wsum + 1.0f : wsum;
      float invd = 1.0f / d;
      a0 *= invd; a1 *= invd;
      *(float2*)&out[(size_t)node * HID + l * 2] = make_float2(a0, a1);
      ps0 += a0; ps1 += a1; q0s += a0 * a0; q1s += a1 * a1;
    }
  }
  red[0][wv][l][0] = ps0; red[0][wv][l][1] = ps1;
  red[1][wv][l][0] = q0s; red[1][wv][l][1] = q1s;
  __syncthreads();
  if (wv == 0) {
    float s0 = 0, s1 = 0, t0 = 0, t1 = 0;
#pragma unroll
    for (int k = 0; k < 4; ++k) {
      s0 += red[0][k][l][0]; s1 += red[0][k][l][1];
      t0 += red[1][k][l][0]; t1 += red[1][k][l][1];
    }
    atomicAdd(&gsum[l * 2], s0); atomicAdd(&gsum[l * 2 + 1], s1);
    atomicAdd(&gsq[l * 2], t0);  atomicAdd(&gsq[l * 2 + 1], t1);
  }
}

// ---------------- final in-place affine on d_out ----------------
__global__ void k_final(float* __restrict__ out, const float* __restrict__ A,
                        const float* __restrict__ C, int n) {
  __shared__ float la[HID], lc[HID];
  if (threadIdx.x < HID) { la[threadIdx.x] = A[threadIdx.x]; lc[threadIdx.x] = C[threadIdx.x]; }
  __syncthreads();
  int total = n * 32;  // float4 count
  for (int i = blockIdx.x * blockDim.x + threadIdx.x; i < total; i += gridDim.x * blockDim.x) {
    float4 v = *(float4*)(out + (size_t)i * 4);
    int cg = (i & 31) * 4;
    v.x = fmaf(la[cg + 0], v.x, lc[cg + 0]);
    v.y = fmaf(la[cg + 1], v.y, lc[cg + 1]);
    v.z = fmaf(la[cg + 2], v.z, lc[cg + 2]);
    v.w = fmaf(la[cg + 3], v.w, lc[cg + 3]);
    *(float4*)(out + (size_t)i * 4) = v;
  }
}

extern "C" void kernel_launch(void* const* d_in, const int* in_sizes, int n_in,
                              void* d_out, int out_size, void* d_ws, size_t ws_size,
                              hipStream_t stream) {
  const int* x = (const int*)d_in[0];
  const int* ei = (const int*)d_in[1];
  const float* ew = (const float*)d_in[2];
  const float* emb = (const float*)d_in[3];
  const float* gw = (const float*)d_in[4];
  const float* gb = (const float*)d_in[5];
  const float* gms = (const float*)d_in[6];
  float* out = (float*)d_out;

  const int n = in_sizes[0];        // 100000
  const int e = in_sizes[1] / 2;    // 1600000
  const int* row = ei;
  const int* col = ei + e;

  // workspace layout, in 4-byte units, 128B-aligned chunks
  float* wsf = (float*)d_ws;
  size_t o = 0;
  auto alloc = [&](size_t elems) -> size_t { size_t r = o; o += ((elems + 31) & ~(size_t)31); return r; };
  size_t cnt_o = alloc(n + 1);
  size_t hist_o = alloc(65);
  size_t sum2_o = alloc(HID), sq2_o = alloc(HID), sum4_o = alloc(HID), sq4_o = alloc(HID);
  size_t hmax_o = alloc(HID);
  size_t wc_o = alloc(32);                   // work-steal counters (wc[0]=spmm1, wc[1]=spmm2)
  size_t zero_end = o;                       // everything above must be zeroed
  size_t A12_o = alloc(HID), C12_o = alloc(HID), A34_o = alloc(HID), C34_o = alloc(HID);
  size_t Aq_o = alloc(HID), qinv_o = alloc(HID);
  size_t rowptr_o = alloc(n + 1);
  size_t slot_o = alloc(e);
  size_t bsum_o = alloc(64);
  size_t emb1b_o = alloc(65 * HID / 2);      // bf16 pairs
  size_t sedge_o = alloc((size_t)e * 2);     // int2 per edge
  size_t h2b_o = alloc((size_t)n * HID / 2); // bf16 pairs (uint) per 2 elements
  size_t qmat_o = alloc((size_t)n * HID / 4); // int8 per element (uint per 4)

  int* cnt = (int*)(wsf + cnt_o);
  int* hist = (int*)(wsf + hist_o);
  float* sum2 = wsf + sum2_o; float* sq2 = wsf + sq2_o;
  float* sum4 = wsf + sum4_o; float* sq4 = wsf + sq4_o;
  unsigned* hmax = (unsigned*)(wsf + hmax_o);
  int* wc = (int*)(wsf + wc_o);
  float* A12 = wsf + A12_o; float* C12 = wsf + C12_o;
  float* A34 = wsf + A34_o; float* C34 = wsf + C34_o;
  float* Aq = wsf + Aq_o; float* qinv = wsf + qinv_o;
  int* rowptr = (int*)(wsf + rowptr_o);
  int* slot = (int*)(wsf + slot_o);
  int* bsum = (int*)(wsf + bsum_o);
  unsigned* emb1b = (unsigned*)(wsf + emb1b_o);
  int2* sedge = (int2*)(wsf + sedge_o);
  unsigned* h2b = (unsigned*)(wsf + h2b_o);
  unsigned* qmat = (unsigned*)(wsf + qmat_o);

  const float invN = 1.0f / (float)n;
  const int nblk = 2048;

  hipMemsetAsync(d_ws, 0, zero_end * sizeof(float), stream);
  k_histcnt<<<2048, 256, 0, stream>>>(x, n, row, e, hist, cnt, slot);
  int nb = (n + 1 + 2047) / 2048;
  k_scan_partial<<<nb, 256, 0, stream>>>(cnt, n + 1, bsum);
  k_scan_bsum<<<1, 64, 0, stream>>>(bsum, nb);
  k_scan_final<<<nb, 256, 0, stream>>>(cnt, n + 1, bsum, rowptr);
  k_scatter<<<2048, 256, 0, stream>>>(row, col, ew, x, rowptr, slot, e, sedge);
  k_gn0<<<1, 64, 0, stream>>>(emb, hist, gw, gb, gms, invN, emb1b);
  k_spmm1<<<nblk, 256, 0, stream>>>(rowptr, sedge, emb1b, n, &wc[0], h2b, sum2, sq2, hmax);
  k_gnchain<<<1, HID, 0, stream>>>(sum2, sq2, invN, gw, gb, gms, 1, 2, A12, C12,
                                   (const float*)hmax, Aq, qinv);
  k_quant<<<2048, 256, 0, stream>>>(h2b, qinv, n, qmat);
  k_spmm2<<<nblk, 256, 0, stream>>>(rowptr, sedge, (const unsigned char*)qmat, Aq, C12,
                                    n, &wc[1], out, sum4, sq4);
  k_gnchain<<<1, HID, 0, stream>>>(sum4, sq4, invN, gw, gb, gms, 3, 4, A34, C34,
                                   nullptr, nullptr, nullptr);
  k_final<<<2048, 256, 0, stream>>>(out, A34, C34, n);
}